// Round 9
// baseline (259.923 us; speedup 1.0000x reference)
//
#include <hip/hip_runtime.h>
#include <hip/hip_fp16.h>
#include <math.h>

#define CAP 64          // max incidences per node (mean deg = 8)
#define D1 128
#define D2 16
#define C_OUT 40
#define K_EDGE 32
#define CLAMP_LO 1e-7f
#define CLAMP_HI 10.0f
#define SQRT_INV31 0.1796053020267749f   // sqrt(1/31)

typedef unsigned short ushort_t;
typedef _Float16 hv2 __attribute__((ext_vector_type(2)));
typedef _Float16 hv8 __attribute__((ext_vector_type(8)));   // 16 B

__device__ __forceinline__ hv2 hv2_zero() {
    hv2 z; z.x = (_Float16)0; z.y = (_Float16)0; return z;
}

__device__ __forceinline__ hv8 shflx_hv8(hv8 v, int m) {
    union { hv8 h; int i[4]; } u; u.h = v;
#pragma unroll
    for (int k = 0; k < 4; k++) u.i[k] = __shfl_xor(u.i[k], m, 64);
    return u.h;
}

// Fused setup: clip+square -> Hp (fp16), incidence-list build (uint16 edge
// ids), W1 transpose, zero rows of S/S2.
__global__ __launch_bounds__(256) void k_setup(const float* __restrict__ x,
                                               hv2* __restrict__ Hp,
                                               const int* __restrict__ idx,
                                               int* __restrict__ deg,
                                               ushort_t* __restrict__ lst,
                                               const float* __restrict__ W1,
                                               float* __restrict__ W1t,
                                               hv2* __restrict__ S,
                                               float* __restrict__ S2,
                                               int n4, int total, int E) {
    int i = blockIdx.x * 256 + threadIdx.x;
    if (i < n4) {                                  // clip + square, 4 floats
        float4 v = ((const float4*)x)[i];
        v.x = fminf(fmaxf(v.x, CLAMP_LO), CLAMP_HI);
        v.y = fminf(fmaxf(v.y, CLAMP_LO), CLAMP_HI);
        v.z = fminf(fmaxf(v.z, CLAMP_LO), CLAMP_HI);
        v.w = fminf(fmaxf(v.w, CLAMP_LO), CLAMP_HI);
        hv2 h0; h0.x = (_Float16)(v.x * v.x); h0.y = (_Float16)(v.y * v.y);
        hv2 h1; h1.x = (_Float16)(v.z * v.z); h1.y = (_Float16)(v.w * v.w);
        Hp[2 * i] = h0; Hp[2 * i + 1] = h1;
    }
    if (i < total) {                               // incidence build
        int n = idx[i];
        int e = i >> 5;                            // k = 32
        int pos = atomicAdd(&deg[n], 1);
        if (pos < CAP) lst[n * CAP + pos] = (ushort_t)e;
    }
    if (i < D1 * D2) W1t[(i & 15) * D1 + (i >> 4)] = W1[i];
    if (i < 64) S[(size_t)E * 64 + i] = hv2_zero();
    if (i < D2) S2[(size_t)E * D2 + i] = 0.0f;
}

// S[e,:] = sum of Hp[node,:] over the edge's 32 nodes. FOUR edges per wave,
// group g (16 lanes) owns edge eA+g; lane loads 16 B (8 cols) per row.
// ids: one int2 load per lane (slots 2q,2q+1), distributed by 1 bpermute/step.
__global__ __launch_bounds__(256) void k_edge_sum(const hv8* __restrict__ Hp,
                                                  const int* __restrict__ idx,
                                                  hv8* __restrict__ S, int E) {
    int w = threadIdx.x >> 6;
    int lane = threadIdx.x & 63;
    int q = lane & 15, g = lane >> 4;
    int eA = (blockIdx.x * 4 + w) * 4;
    if (eA + 4 > E) eA = E - 4;                  // overlap duplicates, benign
    int2 id2 = *(const int2*)(idx + (size_t)(eA + g) * K_EDGE + 2 * q);
    int idlo = id2.x, idhi = id2.y;              // slots 2q, 2q+1 of edge eA+g

    hv8 accA = {0,0,0,0,0,0,0,0}, accB = {0,0,0,0,0,0,0,0};
#pragma unroll
    for (int j = 0; j < K_EDGE; j++) {
        int src = (lane & 48) + (j >> 1);        // lane g*16 + j/2 of this group
        int id = __shfl((j & 1) ? idhi : idlo, src, 64);
        hv8 hvv = Hp[(size_t)id * 16 + q];
        if (j < 16) accA += hvv; else accB += hvv;   // 2-group fp16 accumulation
    }
    S[(size_t)(eA + g) * 16 + q] = accA + accB;
}

// Fused layer-1 node kernel. TWO nodes per wave; 16B S-gathers: group g
// (16 lanes) covers slot rows {g,4+g,8+g,12+g} of each node, lane q holds
// cols 8q..8q+7. Zero-row padding: unused slots carry edge id E (row E of S
// zeroed) so sqrt(max(0-hp,0)) == 0. Cross-group shfl_xor reduce.
__global__ __launch_bounds__(256) void k_node1(const hv8* __restrict__ Hp,
                                               const hv8* __restrict__ S,
                                               const int* __restrict__ deg,
                                               const ushort_t* __restrict__ lst,
                                               const float* __restrict__ W1t,
                                               const float* __restrict__ b1,
                                               _Float16* __restrict__ Hp2, int N, int E) {
    int w = threadIdx.x >> 6;
    int lane = threadIdx.x & 63;
    int pair = blockIdx.x * 4 + w;              // wave handles nodes 2p, 2p+1
    int n0 = pair * 2, n1 = n0 + 1;             // N even
    int q = lane & 15, g = lane >> 4;

    int2 dg2 = ((const int2*)deg)[pair];
    int dg0 = min(dg2.x, CAP), dg1 = min(dg2.y, CAP);
    int nodesel = (lane < 16) ? n0 : n1;
    ushort_t idu = (lane < 32) ? lst[nodesel * CAP + q] : (ushort_t)0;
    int dsel = (lane < 16) ? dg0 : dg1;
    int e_sel = (lane < 32 && q < dsel) ? (int)idu : E;

    // distribute 8 slot ids to this group (independent bpermutes)
    int ea[4], eb[4];
#pragma unroll
    for (int t = 0; t < 4; t++) {
        ea[t] = __shfl(e_sel, g + 4 * t, 64);        // node0 slots
        eb[t] = __shfl(e_sel, 16 + g + 4 * t, 64);   // node1 slots
    }

    hv8 hpa = Hp[(size_t)n0 * 16 + q];
    hv8 hpb = Hp[(size_t)n1 * 16 + q];

    hv8 sva[4], svb[4];
#pragma unroll
    for (int t = 0; t < 4; t++) sva[t] = S[(size_t)ea[t] * 16 + q];
#pragma unroll
    for (int t = 0; t < 4; t++) svb[t] = S[(size_t)eb[t] * 16 + q];

    hv8 z = {0,0,0,0,0,0,0,0};
    hv8 A0 = z, A1 = z;
#pragma unroll
    for (int t = 0; t < 4; t++) {
        A0 += __builtin_elementwise_sqrt(__builtin_elementwise_max(sva[t] - hpa, z));
        A1 += __builtin_elementwise_sqrt(__builtin_elementwise_max(svb[t] - hpb, z));
    }
    if (g == 0) {                                // rare tails, counted once
        for (int t = 16; t < dg0; t++) {
            int e = lst[n0 * CAP + t];
            A0 += __builtin_elementwise_sqrt(
                __builtin_elementwise_max(S[(size_t)e * 16 + q] - hpa, z));
        }
        for (int t = 16; t < dg1; t++) {
            int e = lst[n1 * CAP + t];
            A1 += __builtin_elementwise_sqrt(
                __builtin_elementwise_max(S[(size_t)e * 16 + q] - hpb, z));
        }
    }
    // cross-group reduce: sum slot-partials over the 4 groups
    A0 += shflx_hv8(A0, 16); A0 += shflx_hv8(A0, 32);
    A1 += shflx_hv8(A1, 16); A1 += shflx_hv8(A1, 32);

    float ns0[8], ns1[8], sum0 = 0.0f, sum1 = 0.0f;
#pragma unroll
    for (int i = 0; i < 8; i++) {
        ns0[i] = __builtin_amdgcn_sqrtf((float)hpa[i]) + (float)A0[i] * SQRT_INV31;
        ns1[i] = __builtin_amdgcn_sqrtf((float)hpb[i]) + (float)A1[i] * SQRT_INV31;
        sum0 += ns0[i]; sum1 += ns1[i];
    }
    // rowsum: butterfly within the 16-lane group covers all 128 cols
#pragma unroll
    for (int m = 1; m < 16; m <<= 1) {
        sum0 += __shfl_xor(sum0, m, 64);
        sum1 += __shfl_xor(sum1, m, 64);
    }
    float r0 = __builtin_amdgcn_rcpf(sum0);
    float r1 = __builtin_amdgcn_rcpf(sum1);

    __shared__ float AHs[4][2][D1];             // wave-private
    if (g == 0) {
        float4 v0a = {ns0[0], ns0[1], ns0[2], ns0[3]};
        float4 v0b = {ns0[4], ns0[5], ns0[6], ns0[7]};
        float4 v1a = {ns1[0], ns1[1], ns1[2], ns1[3]};
        float4 v1b = {ns1[4], ns1[5], ns1[6], ns1[7]};
        *(float4*)&AHs[w][0][q * 8]     = v0a;
        *(float4*)&AHs[w][0][q * 8 + 4] = v0b;
        *(float4*)&AHs[w][1][q * 8]     = v1a;
        *(float4*)&AHs[w][1][q * 8 + 4] = v1b;
    }
    __threadfence_block();                      // LDS visibility within wave

    // ns[128] @ W1[128,16] for both nodes, sharing the W1t fragment.
    const float4* a0p = (const float4*)(&AHs[w][0][g * 32]);
    const float4* a1p = (const float4*)(&AHs[w][1][g * 32]);
    const float4* w1p = (const float4*)(W1t + q * D1 + g * 32);
    float p0 = 0.0f, p1 = 0.0f;
#pragma unroll
    for (int tt = 0; tt < 8; tt++) {
        float4 wv = w1p[tt];
        float4 x0 = a0p[tt];
        float4 x1 = a1p[tt];
        p0 += x0.x * wv.x + x0.y * wv.y + x0.z * wv.z + x0.w * wv.w;
        p1 += x1.x * wv.x + x1.y * wv.y + x1.z * wv.z + x1.w * wv.w;
    }
    p0 += __shfl_xor(p0, 16, 64);
    p0 += __shfl_xor(p0, 32, 64);
    p1 += __shfl_xor(p1, 16, 64);
    p1 += __shfl_xor(p1, 32, 64);
    if (lane < D2) {
        float bb = b1[q];
        float o0 = bb + p0 * r0;
        float o1 = bb + p1 * r1;
        float cl0 = fminf(fmaxf(o0, CLAMP_LO), CLAMP_HI);   // relu + next clip
        float cl1 = fminf(fmaxf(o1, CLAMP_LO), CLAMP_HI);
        Hp2[(size_t)n0 * D2 + q] = (_Float16)(cl0 * cl0);
        Hp2[(size_t)n1 * D2 + q] = (_Float16)(cl1 * cl1);
    }
}

// S2[e,:] = sum over 32 nodes of Hp2[node,:] (fp16 in, fp32 out). 8 lanes
// per edge (2 cols packed per lane), 8 edges per wave, 32 per block.
__global__ __launch_bounds__(256) void k_edge_sum2(const hv2* __restrict__ Hp2v,
                                                   const int* __restrict__ idx,
                                                   float2* __restrict__ S2v, int E) {
    int w = threadIdx.x >> 6;
    int lane = threadIdx.x & 63;
    int sub = lane >> 3;
    int cp = lane & 7;
    int e = (blockIdx.x * 4 + w) * 8 + sub;
    if (e >= E) e = E - 1;                       // duplicate, benign
    const int* ip = idx + (size_t)e * K_EDGE;
    hv2 g0 = hv2_zero(), g1 = hv2_zero();
#pragma unroll
    for (int j = 0; j < 16; j++)  g0 += Hp2v[(size_t)ip[j] * 8 + cp];
#pragma unroll
    for (int j = 16; j < 32; j++) g1 += Hp2v[(size_t)ip[j] * 8 + cp];
    float2 s; s.x = (float)g0.x + (float)g1.x; s.y = (float)g0.y + (float)g1.y;
    S2v[(size_t)e * 8 + cp] = s;
}

// Fused layer-2 node kernel. TWO nodes per wave: node = lane bit 5, two
// 16-lane subgroups per node split the 16 gather slots. uint16 lst.
__global__ __launch_bounds__(256) void k_node2(const _Float16* __restrict__ Hp2,
                                               const float* __restrict__ S2,
                                               const int* __restrict__ deg,
                                               const ushort_t* __restrict__ lst,
                                               const float* __restrict__ W2,
                                               const float* __restrict__ b2,
                                               float* __restrict__ out, int N, int E) {
    int w = threadIdx.x >> 6;
    int lane = threadIdx.x & 63;
    int pair = blockIdx.x * 4 + w;
    int n0 = pair * 2, n1 = n0 + 1;
    int col = lane & 15;
    int node = lane >> 5;                       // 0 or 1
    int gg = (lane >> 4) & 1;                   // subgroup within node
    int nn = node ? n1 : n0;

    int2 dg2 = ((const int2*)deg)[pair];
    int dg0 = min(dg2.x, CAP), dg1 = min(dg2.y, CAP);
    int sl = lane & 15;
    ushort_t idu = (lane < 32) ? lst[((lane < 16) ? n0 : n1) * CAP + sl] : (ushort_t)0;
    int dsel = (lane < 16) ? dg0 : dg1;
    int e_sel = (lane < 32 && sl < dsel) ? (int)idu : E;   // E = zero row of S2

    float hp = (float)Hp2[(size_t)nn * D2 + col];
    int dgn = node ? dg1 : dg0;

    // 8 slots per lane: {2t+gg}, t=0..7, from this node's 16 slots
    int ev[8];
#pragma unroll
    for (int t = 0; t < 8; t++) ev[t] = __shfl(e_sel, node * 16 + 2 * t + gg, 64);
    float sv[8];
#pragma unroll
    for (int t = 0; t < 8; t++) sv[t] = S2[(size_t)ev[t] * D2 + col];

    float acc = 0.0f;
#pragma unroll
    for (int t = 0; t < 8; t++)
        acc += __builtin_amdgcn_sqrtf(fmaxf(sv[t] - hp, 0.0f));
    for (int t = 16; t < dgn; t++) {            // rare tail; add once (gg==0)
        int e = lst[nn * CAP + t];
        float s = S2[(size_t)e * D2 + col];
        if (gg == 0) acc += __builtin_amdgcn_sqrtf(fmaxf(s - hp, 0.0f));
    }
    acc += __shfl_xor(acc, 16, 64);             // combine the node's 2 subgroups
    float ns = __builtin_amdgcn_sqrtf(hp) + acc * SQRT_INV31;

    float v = ns;
#pragma unroll
    for (int m = 1; m < 16; m <<= 1) v += __shfl_xor(v, m, 64);  // rowsum (16 cols)
    float r = __builtin_amdgcn_rcpf(v);

    __shared__ float AHs[4][2][D2];             // wave-private
    if (gg == 0) AHs[w][node][col] = ns * r;
    __threadfence_block();

    if (lane < C_OUT) {
        float o0 = b2[lane], o1 = o0;
#pragma unroll
        for (int i = 0; i < D2; i++) {
            float wv = W2[i * C_OUT + lane];
            o0 += AHs[w][0][i] * wv;
            o1 += AHs[w][1][i] * wv;
        }
        out[(size_t)n0 * C_OUT + lane] = o0;
        out[(size_t)n1 * C_OUT + lane] = o1;
    }
}

extern "C" void kernel_launch(void* const* d_in, const int* in_sizes, int n_in,
                              void* d_out, int out_size, void* d_ws, size_t ws_size,
                              hipStream_t stream) {
    const float* x   = (const float*)d_in[0];
    const int*   idx = (const int*)d_in[1];
    const float* W1  = (const float*)d_in[2];
    const float* b1  = (const float*)d_in[3];
    const float* W2  = (const float*)d_in[4];
    const float* b2  = (const float*)d_in[5];
    float* out = (float*)d_out;

    int N = in_sizes[0] / D1;     // 100000
    int E = in_sizes[1] / K_EDGE; // 25000

    // workspace layout (S and S2 have one extra zero row at index E)
    hv2* Hp = (hv2*)d_ws;                                   // N*64
    hv2* S  = Hp + (size_t)N * 64;                          // (E+1)*64
    _Float16* Hp2h = (_Float16*)(S + (size_t)(E + 1) * 64); // N*16
    float* S2   = (float*)(Hp2h + (size_t)N * D2);          // (E+1)*16
    float* W1t  = S2 + (size_t)(E + 1) * D2;                // 16*128
    int*   deg  = (int*)(W1t + D1 * D2);                    // N ints
    ushort_t* lst = (ushort_t*)(deg + N);                   // N*CAP uint16

    int total = E * K_EDGE;        // 800000
    int n4 = N * D1 / 4;           // 3200000

    (void)hipMemsetAsync(deg, 0, (size_t)N * sizeof(int), stream);
    k_setup<<<(n4 + 255) / 256, 256, 0, stream>>>(x, Hp, idx, deg, lst, W1, W1t,
                                                  S, S2, n4, total, E);
    k_edge_sum<<<(E + 15) / 16, 256, 0, stream>>>((const hv8*)Hp, idx, (hv8*)S, E);
    k_node1<<<N / 8, 256, 0, stream>>>((const hv8*)Hp, (const hv8*)S, deg, lst,
                                       W1t, b1, Hp2h, N, E);
    k_edge_sum2<<<(E + 31) / 32, 256, 0, stream>>>((const hv2*)Hp2h, idx, (float2*)S2, E);
    k_node2<<<N / 8, 256, 0, stream>>>(Hp2h, S2, deg, lst, W2, b2, out, N, E);
}